// Round 7
// baseline (38.151 us; speedup 1.0000x reference)
//
#include <hip/hip_runtime.h>

#define CC 64
#define HH 64
#define WW 64
#define OO 128
#define HW (HH * WW)

typedef float f32x4 __attribute__((ext_vector_type(4)));

// lane L (within a 16-lane DPP row) gets src from lane L-1; first lane keeps edge.
__device__ __forceinline__ float dpp_shr1(float src, float edge) {
    int old = __builtin_bit_cast(int, edge);
    int s   = __builtin_bit_cast(int, src);
    int r = __builtin_amdgcn_update_dpp(old, s, 0x111, 0xF, 0xF, false); // row_shr:1
    return __builtin_bit_cast(float, r);
}
// lane L gets src from lane L+1; last lane of each 16-lane row keeps edge.
__device__ __forceinline__ float dpp_shl1(float src, float edge) {
    int old = __builtin_bit_cast(int, edge);
    int s   = __builtin_bit_cast(int, src);
    int r = __builtin_amdgcn_update_dpp(old, s, 0x101, 0xF, 0xF, false); // row_shl:1
    return __builtin_bit_cast(float, r);
}

struct Batch { float4 q[9]; int j[9]; };   // 36 VGPR + uniform j's (SGPR)

__device__ __forceinline__ void load_taps(Batch& B, const float* __restrict__ xb,
                                          const int* __restrict__ conn, int o,
                                          const int ro0, const int ro1, const int ro2) {
    #pragma unroll
    for (int t = 0; t < 9; ++t) {
        const int v  = conn[o * 9 + t];     // uniform -> s_load (36 contiguous dwords/block)
        const int c  = v / 9;
        const int r9 = v - c * 9;
        const int i  = r9 / 3;
        B.j[t] = r9 - i * 3;
        const int ro = (i == 0) ? ro0 : ((i == 1) ? ro1 : ro2);
        B.q[t] = *(const float4*)(xb + c * HW + ro);   // coalesced 1KB wave gather
    }
}

__device__ __forceinline__ f32x4 compute_o(const Batch& B,
                                           const float* __restrict__ w1,
                                           const float* __restrict__ w2, int o) {
    float r0, r1, r2, r3;
    #pragma unroll
    for (int p = 0; p < 3; ++p) {
        float e0, e1, e2, e3;
        #pragma unroll
        for (int tt = 0; tt < 3; ++tt) {
            const int t = p * 3 + tt;
            const float w1v = w1[o * 9 + t];            // uniform
            const float4 q = B.q[t];
            float v0, v1, v2, v3;
            if (B.j[t] == 0) {                          // uniform branch
                const float le = dpp_shr1(q.w, q.x);
                v0 = le;  v1 = q.x; v2 = q.y; v3 = q.z;
            } else if (B.j[t] == 1) {
                v0 = q.x; v1 = q.y; v2 = q.z; v3 = q.w;
            } else {
                const float re = dpp_shl1(q.x, q.w);
                v0 = q.y; v1 = q.z; v2 = q.w; v3 = re;
            }
            const float d0 = fabsf(v0 - w1v);
            const float d1 = fabsf(v1 - w1v);
            const float d2 = fabsf(v2 - w1v);
            const float d3 = fabsf(v3 - w1v);
            if (tt == 0) { e0 = d0; e1 = d1; e2 = d2; e3 = d3; }
            else {
                e0 = fmaxf(e0, d0); e1 = fmaxf(e1, d1);
                e2 = fmaxf(e2, d2); e3 = fmaxf(e3, d3);
            }
        }
        const float w2v = w2[o * 3 + p];                // uniform
        const float m0 = fabsf(e0 - w2v);
        const float m1 = fabsf(e1 - w2v);
        const float m2 = fabsf(e2 - w2v);
        const float m3 = fabsf(e3 - w2v);
        if (p == 0) { r0 = m0; r1 = m1; r2 = m2; r3 = m3; }
        else {
            r0 = fminf(r0, m0); r1 = fminf(r1, m1);
            r2 = fminf(r2, m2); r3 = fminf(r3, m3);
        }
    }
    f32x4 res; res.x = r0; res.y = r1; res.z = r2; res.w = r3;
    return res;
}

// Block: 256 threads = 16 image rows x 16 lanes; lane owns cols 4L..4L+3.
// Grid: 2048 = 32 o-chunks (4 consecutive o) * 64 regions; XCD = region % 8.
// Explicit 2-deep pipeline: batch o+1's 9 gathers in flight during compute of o.
__global__ __launch_bounds__(256, 4) void minimax_conv_kernel(
    const float* __restrict__ x, const float* __restrict__ w1,
    const float* __restrict__ w2, const int* __restrict__ conn,
    float* __restrict__ out)
{
    const int tid  = threadIdx.x;
    const int L    = tid & 15;        // column group within row
    const int hrow = tid >> 4;        // 0..15 row within block
    const int bid = blockIdx.x;
    const int ochunk = bid >> 6;      // 0..31 : 4 consecutive o each
    const int region = bid & 63;
    const int b  = region >> 2;
    const int h0 = (region & 3) * 16;
    const int h  = h0 + hrow;

    // per-lane clamped row offsets (elements) for kernel row i = 0,1,2
    int r0i = h - 1;     r0i = r0i < 0 ? 0 : r0i;
    int r2i = h + 1;     r2i = r2i > HH - 1 ? HH - 1 : r2i;
    const int ro0 = r0i * WW + 4 * L;
    const int ro1 = h   * WW + 4 * L;
    const int ro2 = r2i * WW + 4 * L;

    const float* xb = x + (size_t)b * (CC * HW);
    const int ob = ochunk * 4;
    float* outb = out + (((size_t)b * OO + ob) * HH + h) * WW + 4 * L;
    const size_t ostride = (size_t)HW;   // next o

    Batch B0, B1;
    load_taps(B0, xb, conn, ob + 0, ro0, ro1, ro2);
    load_taps(B1, xb, conn, ob + 1, ro0, ro1, ro2);

    f32x4 r;
    r = compute_o(B0, w1, w2, ob + 0);
    __builtin_nontemporal_store(r, (f32x4*)(outb + 0 * ostride));
    load_taps(B0, xb, conn, ob + 2, ro0, ro1, ro2);

    r = compute_o(B1, w1, w2, ob + 1);
    __builtin_nontemporal_store(r, (f32x4*)(outb + 1 * ostride));
    load_taps(B1, xb, conn, ob + 3, ro0, ro1, ro2);

    r = compute_o(B0, w1, w2, ob + 2);
    __builtin_nontemporal_store(r, (f32x4*)(outb + 2 * ostride));

    r = compute_o(B1, w1, w2, ob + 3);
    __builtin_nontemporal_store(r, (f32x4*)(outb + 3 * ostride));
}

extern "C" void kernel_launch(void* const* d_in, const int* in_sizes, int n_in,
                              void* d_out, int out_size, void* d_ws, size_t ws_size,
                              hipStream_t stream) {
    const float* x    = (const float*)d_in[0];
    const float* w1   = (const float*)d_in[1];
    const float* w2   = (const float*)d_in[2];
    const int*   conn = (const int*)d_in[3];
    float* out = (float*)d_out;

    const int blocks = 32 * 64;   // o-chunks * regions = 2048
    minimax_conv_kernel<<<blocks, 256, 0, stream>>>(x, w1, w2, conn, out);
}

// Round 8
// 32.440 us; speedup vs baseline: 1.1761x; 1.1761x over previous
//
#include <hip/hip_runtime.h>

#define CC 64
#define HH 64
#define WW 64
#define OO 128
#define HW (HH * WW)

typedef float f32x4 __attribute__((ext_vector_type(4)));

// lane L (within a 16-lane DPP row) gets src from lane L-1; first lane keeps edge.
__device__ __forceinline__ float dpp_shr1(float src, float edge) {
    int old = __builtin_bit_cast(int, edge);
    int s   = __builtin_bit_cast(int, src);
    int r = __builtin_amdgcn_update_dpp(old, s, 0x111, 0xF, 0xF, false); // row_shr:1
    return __builtin_bit_cast(float, r);
}
// lane L gets src from lane L+1; last lane of each 16-lane row keeps edge.
__device__ __forceinline__ float dpp_shl1(float src, float edge) {
    int old = __builtin_bit_cast(int, edge);
    int s   = __builtin_bit_cast(int, src);
    int r = __builtin_amdgcn_update_dpp(old, s, 0x101, 0xF, 0xF, false); // row_shl:1
    return __builtin_bit_cast(float, r);
}

// One o per WAVE: 9 gathers -> compute -> store -> retire. Latency hiding via
// pure TLP (8 waves/SIMD resident, ~288 gathers in flight per CU), no
// intra-wave pipelining (R7 showed the compiler can't hold 2 batches live).
// Block: 256 thr = 4 waves; wave wv does o = ochunk*4+wv on a 4-row strip.
// Lane: rloc(0..3) = rows h0..h0+3, L(0..15) = col group 4L..4L+3.
// Grid: 8192 = 32 ochunks * 256 regions (b * 16 strips); XCD = bid%8 = strip%8,
// per-XCD slab working set ~3.1 MB (fits 4 MB L2). nt-stores bypass L2 so the
// out stream doesn't evict x.
__global__ __launch_bounds__(256) void minimax_conv_kernel(
    const float* __restrict__ x, const float* __restrict__ w1,
    const float* __restrict__ w2, const int* __restrict__ conn,
    float* __restrict__ out)
{
    const int tid  = threadIdx.x;
    const int lane = tid & 63;
    const int wv   = __builtin_amdgcn_readfirstlane(tid >> 6);  // 0..3 uniform
    const int L    = lane & 15;
    const int rloc = lane >> 4;                                  // 0..3

    const int bid = blockIdx.x;
    const int ochunk = bid >> 8;      // 0..31
    const int region = bid & 255;
    const int b  = region >> 4;
    const int h0 = (region & 15) * 4;
    const int h  = h0 + rloc;
    const int o  = ochunk * 4 + wv;   // wave-uniform

    // per-lane clamped row offsets (elements) for kernel row i = 0,1,2
    int r0i = h - 1;     r0i = r0i < 0 ? 0 : r0i;
    int r2i = h + 1;     r2i = r2i > HH - 1 ? HH - 1 : r2i;
    const int ro0 = r0i * WW + 4 * L;
    const int ro1 = h   * WW + 4 * L;
    const int ro2 = r2i * WW + 4 * L;

    const float* xb = x + (size_t)b * (CC * HW);

    // ---- issue all 9 gathers (addresses from uniform s_loads of conn) ----
    float4 q[9];
    int    j[9];
    #pragma unroll
    for (int t = 0; t < 9; ++t) {
        const int v  = conn[o * 9 + t];    // uniform -> s_load
        const int c  = v / 9;
        const int r9 = v - c * 9;
        const int i  = r9 / 3;
        j[t] = r9 - i * 3;
        const int ro = (i == 0) ? ro0 : ((i == 1) ? ro1 : ro2);
        q[t] = *(const float4*)(xb + c * HW + ro);   // coalesced 1KB wave gather
    }

    // ---- minimax compute ----
    float r0, r1, r2, r3;
    #pragma unroll
    for (int p = 0; p < 3; ++p) {
        float e0, e1, e2, e3;
        #pragma unroll
        for (int tt = 0; tt < 3; ++tt) {
            const int t = p * 3 + tt;
            const float w1v = w1[o * 9 + t];           // uniform
            const float4 qq = q[t];
            float v0, v1, v2, v3;
            if (j[t] == 0) {                           // uniform branch
                const float le = dpp_shr1(qq.w, qq.x);
                v0 = le;   v1 = qq.x; v2 = qq.y; v3 = qq.z;
            } else if (j[t] == 1) {
                v0 = qq.x; v1 = qq.y; v2 = qq.z; v3 = qq.w;
            } else {
                const float re = dpp_shl1(qq.x, qq.w);
                v0 = qq.y; v1 = qq.z; v2 = qq.w; v3 = re;
            }
            const float d0 = fabsf(v0 - w1v);
            const float d1 = fabsf(v1 - w1v);
            const float d2 = fabsf(v2 - w1v);
            const float d3 = fabsf(v3 - w1v);
            if (tt == 0) { e0 = d0; e1 = d1; e2 = d2; e3 = d3; }
            else {
                e0 = fmaxf(e0, d0); e1 = fmaxf(e1, d1);
                e2 = fmaxf(e2, d2); e3 = fmaxf(e3, d3);
            }
        }
        const float w2v = w2[o * 3 + p];               // uniform
        const float m0 = fabsf(e0 - w2v);
        const float m1 = fabsf(e1 - w2v);
        const float m2 = fabsf(e2 - w2v);
        const float m3 = fabsf(e3 - w2v);
        if (p == 0) { r0 = m0; r1 = m1; r2 = m2; r3 = m3; }
        else {
            r0 = fminf(r0, m0); r1 = fminf(r1, m1);
            r2 = fminf(r2, m2); r3 = fminf(r3, m3);
        }
    }

    f32x4 res; res.x = r0; res.y = r1; res.z = r2; res.w = r3;
    float* op = out + (((size_t)b * OO + o) * HH + h) * WW + 4 * L;
    __builtin_nontemporal_store(res, (f32x4*)op);
}

extern "C" void kernel_launch(void* const* d_in, const int* in_sizes, int n_in,
                              void* d_out, int out_size, void* d_ws, size_t ws_size,
                              hipStream_t stream) {
    const float* x    = (const float*)d_in[0];
    const float* w1   = (const float*)d_in[1];
    const float* w2   = (const float*)d_in[2];
    const int*   conn = (const int*)d_in[3];
    float* out = (float*)d_out;

    const int blocks = 32 * 256;   // o-chunks * regions = 8192
    minimax_conv_kernel<<<blocks, 256, 0, stream>>>(x, w1, w2, conn, out);
}